// Round 11
// baseline (223.359 us; speedup 1.0000x reference)
//
#include <hip/hip_runtime.h>

// BahdanauAttention_16518444220431 — diagonal-DP recurrence on MI355X (gfx950).
// R21 = R20 (verified 61.4us chain, 512thr/8waves/1-ot-per-wave, 4 waves/SIMD,
// VGPR 64) + CROSS-PHASE B-PREFETCH (R18's mechanism, now affordable).
// R20's decisive result: occupancy 17->34% and the wall DIDN'T move => not
// latency-bound; per-CU pipe accounting at the measured wall (4455 cyc/slot):
// MFMA 2195 (49%, = MfmaUtil), LDS 272 ops x 12 = 3264 (73%) — wall ~= sum
// => near-ZERO pipe overlap (post-barrier read bursts serialize, MFMAs chain
// 1:1 behind). Self-ks (R17 +10%) is the only lever that ever worked =
// reg-sourced MFMAs in front of the read queue. This round: during UP of
// pair k, DOWN's state buffer RB is stable (written pair k-1, behind the
// barrier; UA vs UB distinct objects -> alias-free, race-free). Prefetch 8
// of down's 14 B chunks (slots 2..9, +32 regs, peak ~96-110 vs 128 cap)
// after up's GEMM, pinned above PACKZ by sched_barrier(0); pack VALU + WRITEZ
// cover the latency. Down opens with 10 reg-sourced MFMAs (2 self + 8 pre).
// Numerics identical to R20 (same operands/order): absmax 0.015625.
// Falsified: conflicts (R11), setprio (R11), barrier count (R14), forced
// prefetch at 2w/SIMD (R12/13/18 spill @ ~124+32), fused write (R15 race),
// stagger (R16), full unroll (R19 I$), occupancy-as-lever (R20). PROVEN:
// self-ks (R17), vectorized prep, ~70us harness floor. Tripwire: FETCH>10MB
// = spill -> shrink prefetch to 4 chunks.

typedef __bf16 bf16x8 __attribute__((ext_vector_type(8)));
typedef __bf16 bf16x4 __attribute__((ext_vector_type(4)));
typedef float f32x16 __attribute__((ext_vector_type(16)));
typedef unsigned int uint2v __attribute__((ext_vector_type(2)));

#define MFMA32(a, b, c) __builtin_amdgcn_mfma_f32_32x32x16_bf16(a, b, c, 0, 0, 0)

__device__ __forceinline__ unsigned short f2bf(float f) {
  unsigned int u = __builtin_bit_cast(unsigned int, f);
  u += 0x7fffu + ((u >> 16) & 1u);
  return (unsigned short)(u >> 16);
}

__device__ __forceinline__ unsigned pk2(float a, float b) {
  return (unsigned)f2bf(a) | ((unsigned)f2bf(b) << 16);
}

// ws layout (bf16 elements):
//   [0,65536)        W2 fragments: ((ot*16+ks)*64+lane)*8+j ; o=ot*32+(lane&31), k=ks*16+(lane>>5)*8+j
//   [65536,131072)   W4 fragments, same permutation
//   [131072,135168)  W1-extra frags: lanes<32: j<4 -> W1[o][j], j==4 -> b1[o]+b2[o], else 0
//   [135168,139264)  W3-extra frags: j==4 -> b3[o]+2*b4[o]
__global__ void prep_kernel(const float* __restrict__ W1, const float* __restrict__ b1,
                            const float* __restrict__ W2, const float* __restrict__ b2,
                            const float* __restrict__ W3, const float* __restrict__ b3,
                            const float* __restrict__ W4, const float* __restrict__ b4,
                            unsigned short* __restrict__ ws) {
  int t8 = blockIdx.x * 256 + threadIdx.x;
  if (t8 >= 17408) return;   // 139264 / 8
  int idx = t8 * 8;
  int4 outv;
  if (idx < 131072) {
    const float* W = (idx < 65536) ? W2 : W4;
    int f = (idx & 65535) >> 3;
    int lane = f & 63, slot = f >> 6;
    int ks = slot & 15, ot = slot >> 4;
    int o = ot * 32 + (lane & 31);
    int kbase = ks * 16 + (lane >> 5) * 8;
    const float4* row = (const float4*)(W + o * 256 + kbase);
    float4 v0 = row[0];
    float4 v1 = row[1];
    outv = make_int4((int)pk2(v0.x, v0.y), (int)pk2(v0.z, v0.w),
                     (int)pk2(v1.x, v1.y), (int)pk2(v1.z, v1.w));
  } else {
    int i = idx - 131072;
    bool first = (i < 4096);
    int f = (i & 4095) >> 3;
    int lane = f & 63, ot = f >> 6;
    int o = ot * 32 + (lane & 31);
    outv = make_int4(0, 0, 0, 0);
    if (lane < 32) {
      const float4 wrow = *(const float4*)((first ? W1 : W3) + o * 4);
      float bias = first ? (b1[o] + b2[o]) : (b3[o] + 2.0f * b4[o]);
      outv = make_int4((int)pk2(wrow.x, wrow.y), (int)pk2(wrow.z, wrow.w),
                       (int)pk2(bias, 0.0f), 0);
    }
  }
  *(int4*)(ws + idx) = outv;
}

// ---- Wave model (R20): 512 threads = 8 waves, wave w owns output tile ot=w.
// Self ks = {2w, 2w+1}; w2c slot i = physical ks (2w+i)&15, i<4.
// Streamed A slots 4..15 in 2-slot batches, 3 rotating names.

// Load 2 streamed A slots (i, i+1) into AF[0..1].
#define LOAD_AF(AF, I) { \
    int ka_ = (2 * w + (I)) & 15; \
    AF[0] = __builtin_bit_cast(bf16x8, w2f[(ot * 16 + ka_) * 64 + l]); \
    int kb_ = (2 * w + (I) + 1) & 15; \
    AF[1] = __builtin_bit_cast(bf16x8, w2f[(ot * 16 + kb_) * 64 + l]); }

// One LDS-sourced K-slice: 1 ds_read_b128 feeds 1 MFMA. KSR runtime (addr only).
#define GSTEP(RB, KSR, A0) { \
    bf16x8 bu_ = __builtin_bit_cast(bf16x8, (RB)[(2 * (KSR) + khalf) * 32 + lane31]); \
    acc = MFMA32(A0, bu_, acc); }

// Register-sourced K-slice (B prefetched into named int4 P).
#define GSTEPP(P, A0) { \
    bf16x8 bu_ = __builtin_bit_cast(bf16x8, P); \
    acc = MFMA32(A0, bu_, acc); }

// Self K-slice from zk registers (zero LDS dependency). S literal 0..1.
#define SELFSTEP(ZK, S) { \
    bf16x8 bu_ = __builtin_bit_cast(bf16x8, ZK[S]); \
    acc = MFMA32(w2c[S], bu_, acc); }

// relu + bf16 pack + permlane32_swap into full-int4 B-frag form -> ZK regs.
// ZK[p] = chunk ot*4 + 2p + khalf, row lane31  (self ks = 2w+p).
#define PACKZ(ZK) { \
    unsigned lo[4], hi[4]; \
    _Pragma("unroll") for (int q = 0; q < 4; ++q) { \
      bf16x4 h; \
      h.x = (__bf16)fmaxf(acc[4 * q + 0], 0.0f); \
      h.y = (__bf16)fmaxf(acc[4 * q + 1], 0.0f); \
      h.z = (__bf16)fmaxf(acc[4 * q + 2], 0.0f); \
      h.w = (__bf16)fmaxf(acc[4 * q + 3], 0.0f); \
      uint2 u = __builtin_bit_cast(uint2, h); \
      lo[q] = u.x; hi[q] = u.y; \
    } \
    uint2v r0 = __builtin_amdgcn_permlane32_swap(lo[0], lo[1], false, false); \
    uint2v r1 = __builtin_amdgcn_permlane32_swap(hi[0], hi[1], false, false); \
    ZK[0] = make_int4((int)r0.x, (int)r1.x, (int)r0.y, (int)r1.y); \
    uint2v r2 = __builtin_amdgcn_permlane32_swap(lo[2], lo[3], false, false); \
    uint2v r3 = __builtin_amdgcn_permlane32_swap(hi[2], hi[3], false, false); \
    ZK[1] = make_int4((int)r2.x, (int)r3.x, (int)r2.y, (int)r3.y); }

// Write ZK regs (2 int4) into state buffer WB. Conflict-free 512B runs.
#define WRITEZ(ZK, WB) { \
    (WB)[(ot * 4 + khalf) * 32 + lane31] = ZK[0]; \
    (WB)[(ot * 4 + 2 + khalf) * 32 + lane31] = ZK[1]; }

// xw extra-K term for phase PH at step T.
#define XWSTEP(PH, T) { \
    int widx_ = (PH) == 0 ? (lane31 + (T) - 1) : (lane31 + 17 - (T)); \
    const int4* p_ = (l < 32) ? (xw + widx_) : (&zc); \
    bf16x8 bx_ = __builtin_bit_cast(bf16x8, *p_); \
    acc = MFMA32(w1x, bx_, acc); }

// UP interval of pair T: full GEMM from RA, then prefetch DOWN's B chunks
// (slots 2..9 of RB, stable since last barrier) into p2..p9 BEFORE the pack;
// sched_barrier pins the reads above PACKZ so the pack VALU covers them.
#define INTERVAL_UP(T, RA, WA, RB) { \
  bf16x8 afA[2], afB[2], afC[2]; \
  LOAD_AF(afA, 4) \
  f32x16 acc = {}; \
  XWSTEP(0, T) \
  __builtin_amdgcn_s_setprio(1); \
  SELFSTEP(zkU, 0) SELFSTEP(zkU, 1) \
  LOAD_AF(afB, 6) \
  GSTEP(RA, (2 * w + 2) & 15, w2c[2]) \
  GSTEP(RA, (2 * w + 3) & 15, w2c[3]) \
  LOAD_AF(afC, 8) \
  GSTEP(RA, (2 * w + 4) & 15, afA[0]) \
  GSTEP(RA, (2 * w + 5) & 15, afA[1]) \
  LOAD_AF(afA, 10) \
  GSTEP(RA, (2 * w + 6) & 15, afB[0]) \
  GSTEP(RA, (2 * w + 7) & 15, afB[1]) \
  LOAD_AF(afB, 12) \
  GSTEP(RA, (2 * w + 8) & 15, afC[0]) \
  GSTEP(RA, (2 * w + 9) & 15, afC[1]) \
  LOAD_AF(afC, 14) \
  GSTEP(RA, (2 * w + 10) & 15, afA[0]) \
  GSTEP(RA, (2 * w + 11) & 15, afA[1]) \
  GSTEP(RA, (2 * w + 12) & 15, afB[0]) \
  GSTEP(RA, (2 * w + 13) & 15, afB[1]) \
  GSTEP(RA, (2 * w + 14) & 15, afC[0]) \
  GSTEP(RA, (2 * w + 15) & 15, afC[1]) \
  __builtin_amdgcn_s_setprio(0); \
  p2 = (RB)[(2 * ((2 * w + 2) & 15) + khalf) * 32 + lane31]; \
  p3 = (RB)[(2 * ((2 * w + 3) & 15) + khalf) * 32 + lane31]; \
  p4 = (RB)[(2 * ((2 * w + 4) & 15) + khalf) * 32 + lane31]; \
  p5 = (RB)[(2 * ((2 * w + 5) & 15) + khalf) * 32 + lane31]; \
  p6 = (RB)[(2 * ((2 * w + 6) & 15) + khalf) * 32 + lane31]; \
  p7 = (RB)[(2 * ((2 * w + 7) & 15) + khalf) * 32 + lane31]; \
  p8 = (RB)[(2 * ((2 * w + 8) & 15) + khalf) * 32 + lane31]; \
  p9 = (RB)[(2 * ((2 * w + 9) & 15) + khalf) * 32 + lane31]; \
  __builtin_amdgcn_sched_barrier(0); \
  PACKZ(zkU) \
  WRITEZ(zkU, WA) }

// DOWN interval of pair T: opens with 10 register-sourced MFMAs (2 self +
// 8 prefetched); only slots 10..15 read LDS.
#define INTERVAL_DN(T, RB, WB) { \
  bf16x8 afA[2], afB[2], afC[2]; \
  LOAD_AF(afA, 4) \
  f32x16 acc = {}; \
  XWSTEP(1, T) \
  __builtin_amdgcn_s_setprio(1); \
  SELFSTEP(zkD, 0) SELFSTEP(zkD, 1) \
  LOAD_AF(afB, 6) \
  GSTEPP(p2, w2c[2]) \
  GSTEPP(p3, w2c[3]) \
  LOAD_AF(afC, 8) \
  GSTEPP(p4, afA[0]) \
  GSTEPP(p5, afA[1]) \
  LOAD_AF(afA, 10) \
  GSTEPP(p6, afB[0]) \
  GSTEPP(p7, afB[1]) \
  LOAD_AF(afB, 12) \
  GSTEPP(p8, afC[0]) \
  GSTEPP(p9, afC[1]) \
  LOAD_AF(afC, 14) \
  GSTEP(RB, (2 * w + 10) & 15, afA[0]) \
  GSTEP(RB, (2 * w + 11) & 15, afA[1]) \
  GSTEP(RB, (2 * w + 12) & 15, afB[0]) \
  GSTEP(RB, (2 * w + 13) & 15, afB[1]) \
  GSTEP(RB, (2 * w + 14) & 15, afC[0]) \
  GSTEP(RB, (2 * w + 15) & 15, afC[1]) \
  __builtin_amdgcn_s_setprio(0); \
  PACKZ(zkD) \
  WRITEZ(zkD, WB) }

// Peel interval (T=1): no GEMM.
#define INTERVAL_P(PH, WB, ZK) { \
  f32x16 acc = {}; \
  XWSTEP(PH, 1) \
  PACKZ(ZK) \
  WRITEZ(ZK, WB) }

__global__ __launch_bounds__(512, 4)
void chain_kernel(const float* __restrict__ x, const unsigned short* __restrict__ ws,
                  float* __restrict__ out) {
  // Per-phase double-buffered state, chunk-major: buf[c*32 + r] = bf16 elems
  // [8c..8c+7] of state row r (32 rows per tile). 4 x 16KB = 64KB.
  __shared__ int4 UA[2][1024];
  __shared__ int4 UB[2][1024];
  __shared__ int4 xw[48];   // [x0,x1,x2,x3,1,0,0,0] bf16 chunks, rows j0-8 .. j0+39
  __shared__ int4 zc;

  const int tid = threadIdx.x;
  const int l = tid & 63;
  const int w = tid >> 6;        // 8 waves
  const int ot = w;              // one 32-output tile per wave
  const int lane31 = l & 31;
  const int khalf = l >> 5;
  const int tile = blockIdx.x;
  const int b = tile >> 6;
  const int j0 = (tile & 63) * 32;

  const int4* w2f = (const int4*)ws;
  const int4* w4f = (const int4*)(ws + 65536);
  const int4* w1xg = (const int4*)(ws + 131072);
  const int4* w3xg = (const int4*)(ws + 135168);

  if (tid == 0) zc = make_int4(0, 0, 0, 0);
  if (tid < 48) {
    int j = j0 - 8 + tid;
    int4 c = make_int4(0, 0, 0, 0);
    if (j >= 0 && j < 2048) {
      const float* xb = x + (b * 4) * 2048 + j;
      unsigned short h0 = f2bf(xb[0]);
      unsigned short h1 = f2bf(xb[2048]);
      unsigned short h2 = f2bf(xb[4096]);
      unsigned short h3 = f2bf(xb[6144]);
      c = make_int4((int)(h0 | ((unsigned int)h1 << 16)),
                    (int)(h2 | ((unsigned int)h3 << 16)),
                    0x00003f80, 0);  // chunk[4] = bf16(1.0) multiplies the bias row
    }
    xw[tid] = c;
  }

  // Rotated W2 cache: slot i = physical ks (2w+i)&15; slots 0,1 = SELF ks.
  bf16x8 w2c[4];
  bf16x8 w1x;
  w1x = __builtin_bit_cast(bf16x8, w1xg[ot * 64 + l]);
#pragma unroll
  for (int i = 0; i < 4; ++i) {
    int ksr = (2 * w + i) & 15;
    w2c[i] = __builtin_bit_cast(bf16x8, w2f[(ot * 16 + ksr) * 64 + l]);
  }
  __syncthreads();

  // zkU/zkD: this wave's packed state (B-frag layout), ks slots {2w, 2w+1}.
  // Lifetime: packed at pair k, LDS-written same pair, self-consumed pair k+1.
  int4 zkU[2], zkD[2];

  // ---- pair 0 (T=1): no previous state ----
  INTERVAL_P(0, UA[0], zkU)
  INTERVAL_P(1, UB[0], zkD)
  __syncthreads();

  // ---- pairs 1..7 (T=2..8): rolled loop (R19: unroll hurts I$) ----
#pragma unroll 1
  for (int k = 1; k < 8; ++k) {
    const int4* ra = UA[(k - 1) & 1];
    int4* wa = UA[k & 1];
    const int4* rb = UB[(k - 1) & 1];
    int4* wb = UB[k & 1];
    const int T = k + 1;
    int4 p2, p3, p4, p5, p6, p7, p8, p9;   // cross-phase B prefetch
    INTERVAL_UP(T, ra, wa, rb)
    INTERVAL_DN(T, rb, wb)
    __syncthreads();
  }

  // ---- final: miu^T = relu(W3x + b3 + 2b4 + W4*up(8) + W4*down(8)) ----
  // up(8) in UA[1] + zkU self slots; down(8) in UB[1] + zkD.
  {
    f32x16 acc = {};
    { int widx = lane31 + 8;
      const int4* p_ = (l < 32) ? (xw + widx) : (&zc);
      bf16x8 bx = __builtin_bit_cast(bf16x8, *p_);
      bf16x8 w3x = __builtin_bit_cast(bf16x8, w3xg[ot * 64 + l]);
      acc = MFMA32(w3x, bx, acc); }
    __builtin_amdgcn_s_setprio(1);
#pragma unroll 1
    for (int ph = 0; ph < 2; ++ph) {
      const int4* Sp = ph ? UB[1] : UA[1];
      const int4* zz = ph ? zkD : zkU;
#pragma unroll
      for (int s = 0; s < 2; ++s) {
        int ksr = 2 * w + s;
        bf16x8 af = __builtin_bit_cast(bf16x8, w4f[(ot * 16 + ksr) * 64 + l]);
        bf16x8 bu = __builtin_bit_cast(bf16x8, zz[s]);
        acc = MFMA32(af, bu, acc);
      }
#pragma unroll
      for (int i = 2; i < 16; ++i) {
        int ksr = (2 * w + i) & 15;
        bf16x8 af = __builtin_bit_cast(bf16x8, w4f[(ot * 16 + ksr) * 64 + l]);
        bf16x8 bu = __builtin_bit_cast(bf16x8, Sp[(2 * ksr + khalf) * 32 + lane31]);
        acc = MFMA32(af, bu, acc);
      }
    }
    __builtin_amdgcn_s_setprio(0);
    int pbase = (b * 2048 + j0 + lane31) * 256;
#pragma unroll
    for (int q = 0; q < 4; ++q) {
      int ob = ot * 32 + 8 * q + 4 * khalf;
      float4 v;
      v.x = fmaxf(acc[4 * q + 0], 0.0f);
      v.y = fmaxf(acc[4 * q + 1], 0.0f);
      v.z = fmaxf(acc[4 * q + 2], 0.0f);
      v.w = fmaxf(acc[4 * q + 3], 0.0f);
      *(float4*)(out + pbase + ob) = v;
    }
  }
}

extern "C" void kernel_launch(void* const* d_in, const int* in_sizes, int n_in,
                              void* d_out, int out_size, void* d_ws, size_t ws_size,
                              hipStream_t stream) {
  const float* x  = (const float*)d_in[0];
  const float* W1 = (const float*)d_in[1];
  const float* b1 = (const float*)d_in[2];
  const float* W2 = (const float*)d_in[3];
  const float* b2 = (const float*)d_in[4];
  const float* W3 = (const float*)d_in[5];
  const float* b3 = (const float*)d_in[6];
  const float* W4 = (const float*)d_in[7];
  const float* b4 = (const float*)d_in[8];
  unsigned short* ws = (unsigned short*)d_ws;

  prep_kernel<<<68, 256, 0, stream>>>(W1, b1, W2, b2, W3, b3, W4, b4, ws);
  chain_kernel<<<1024, 512, 0, stream>>>(x, ws, (float*)d_out);
}

// Round 12
// 201.189 us; speedup vs baseline: 1.1102x; 1.1102x over previous
//
#include <hip/hip_runtime.h>

// BahdanauAttention_16518444220431 — diagonal-DP recurrence on MI355X (gfx950).
// R22 = R20 (verified 61.4us chain, 512thr/8waves/1-ot-per-wave, VGPR 64) +
// SPLIT-K DUAL ACCUMULATORS. New theory from R17==R20 (4 dep-chains/SIMD in
// BOTH, same wall, same MfmaUtil ~52%): the kernel is MFMA DEPENDENCY-LATENCY
// bound. All 17 MFMAs/interval chain into one acc; util = nChains*32.3/L =>
// L ~ 250 cyc. Explains: occupancy null (R20: chains/SIMD unchanged), self-ks
// +10% (removed read-latency adder), all scheduling tricks null (chain IS the
// wall). Fix: 2 accs/wave (accA: xw + even slots; accB: self + odd slots),
// summed before pack -> 8 chains/SIMD ~= L/32.3, saturating. +16 VGPR only.
// Same split in final GEMM. Numerics: f32 partial-sum reorder, benign.
// CLOSED FAMILIES: cross-section reg prefetch (R12/13/18/21 ALL spill — even
// at 64-VGPR base, sched_barrier-pinned values go to scratch); fused-pair
// write (R15 race); stagger (R16); full unroll (R19 I$); occupancy (R20).
// PROVEN: self-ks (R17 +10%), vectorized prep, ~70us harness floor.
// Tripwire: FETCH>10MB = spill (not expected at ~85 regs). If neutral:
// dep-latency theory dead too -> revert to R17 verbatim, structure ceiling.

typedef __bf16 bf16x8 __attribute__((ext_vector_type(8)));
typedef __bf16 bf16x4 __attribute__((ext_vector_type(4)));
typedef float f32x16 __attribute__((ext_vector_type(16)));
typedef unsigned int uint2v __attribute__((ext_vector_type(2)));

#define MFMA32(a, b, c) __builtin_amdgcn_mfma_f32_32x32x16_bf16(a, b, c, 0, 0, 0)

__device__ __forceinline__ unsigned short f2bf(float f) {
  unsigned int u = __builtin_bit_cast(unsigned int, f);
  u += 0x7fffu + ((u >> 16) & 1u);
  return (unsigned short)(u >> 16);
}

__device__ __forceinline__ unsigned pk2(float a, float b) {
  return (unsigned)f2bf(a) | ((unsigned)f2bf(b) << 16);
}

// ws layout (bf16 elements):
//   [0,65536)        W2 fragments: ((ot*16+ks)*64+lane)*8+j ; o=ot*32+(lane&31), k=ks*16+(lane>>5)*8+j
//   [65536,131072)   W4 fragments, same permutation
//   [131072,135168)  W1-extra frags: lanes<32: j<4 -> W1[o][j], j==4 -> b1[o]+b2[o], else 0
//   [135168,139264)  W3-extra frags: j==4 -> b3[o]+2*b4[o]
__global__ void prep_kernel(const float* __restrict__ W1, const float* __restrict__ b1,
                            const float* __restrict__ W2, const float* __restrict__ b2,
                            const float* __restrict__ W3, const float* __restrict__ b3,
                            const float* __restrict__ W4, const float* __restrict__ b4,
                            unsigned short* __restrict__ ws) {
  int t8 = blockIdx.x * 256 + threadIdx.x;
  if (t8 >= 17408) return;   // 139264 / 8
  int idx = t8 * 8;
  int4 outv;
  if (idx < 131072) {
    const float* W = (idx < 65536) ? W2 : W4;
    int f = (idx & 65535) >> 3;
    int lane = f & 63, slot = f >> 6;
    int ks = slot & 15, ot = slot >> 4;
    int o = ot * 32 + (lane & 31);
    int kbase = ks * 16 + (lane >> 5) * 8;
    const float4* row = (const float4*)(W + o * 256 + kbase);
    float4 v0 = row[0];
    float4 v1 = row[1];
    outv = make_int4((int)pk2(v0.x, v0.y), (int)pk2(v0.z, v0.w),
                     (int)pk2(v1.x, v1.y), (int)pk2(v1.z, v1.w));
  } else {
    int i = idx - 131072;
    bool first = (i < 4096);
    int f = (i & 4095) >> 3;
    int lane = f & 63, ot = f >> 6;
    int o = ot * 32 + (lane & 31);
    outv = make_int4(0, 0, 0, 0);
    if (lane < 32) {
      const float4 wrow = *(const float4*)((first ? W1 : W3) + o * 4);
      float bias = first ? (b1[o] + b2[o]) : (b3[o] + 2.0f * b4[o]);
      outv = make_int4((int)pk2(wrow.x, wrow.y), (int)pk2(wrow.z, wrow.w),
                       (int)pk2(bias, 0.0f), 0);
    }
  }
  *(int4*)(ws + idx) = outv;
}

// ---- Wave model (R20): 512 threads = 8 waves, wave w owns output tile ot=w.
// Self ks = {2w, 2w+1}; w2c slot i = physical ks (2w+i)&15, i<4.
// Streamed A slots 4..15 in 2-slot batches, 3 rotating names.

// Load 2 streamed A slots (i, i+1) into AF[0..1].
#define LOAD_AF(AF, I) { \
    int ka_ = (2 * w + (I)) & 15; \
    AF[0] = __builtin_bit_cast(bf16x8, w2f[(ot * 16 + ka_) * 64 + l]); \
    int kb_ = (2 * w + (I) + 1) & 15; \
    AF[1] = __builtin_bit_cast(bf16x8, w2f[(ot * 16 + kb_) * 64 + l]); }

// One LDS-sourced K-slice into accumulator ACC. KSR runtime (addr only).
#define GSTEP(RB, KSR, A0, ACC) { \
    bf16x8 bu_ = __builtin_bit_cast(bf16x8, (RB)[(2 * (KSR) + khalf) * 32 + lane31]); \
    ACC = MFMA32(A0, bu_, ACC); }

// Self K-slice from zk registers (zero LDS dependency) into ACC. S literal 0..1.
#define SELFSTEP(ZK, S, ACC) { \
    bf16x8 bu_ = __builtin_bit_cast(bf16x8, ZK[S]); \
    ACC = MFMA32(w2c[S], bu_, ACC); }

// relu + bf16 pack + permlane32_swap into full-int4 B-frag form -> ZK regs.
// ZK[p] = chunk ot*4 + 2p + khalf, row lane31  (self ks = 2w+p).
#define PACKZ(ZK) { \
    unsigned lo[4], hi[4]; \
    _Pragma("unroll") for (int q = 0; q < 4; ++q) { \
      bf16x4 h; \
      h.x = (__bf16)fmaxf(acc[4 * q + 0], 0.0f); \
      h.y = (__bf16)fmaxf(acc[4 * q + 1], 0.0f); \
      h.z = (__bf16)fmaxf(acc[4 * q + 2], 0.0f); \
      h.w = (__bf16)fmaxf(acc[4 * q + 3], 0.0f); \
      uint2 u = __builtin_bit_cast(uint2, h); \
      lo[q] = u.x; hi[q] = u.y; \
    } \
    uint2v r0 = __builtin_amdgcn_permlane32_swap(lo[0], lo[1], false, false); \
    uint2v r1 = __builtin_amdgcn_permlane32_swap(hi[0], hi[1], false, false); \
    ZK[0] = make_int4((int)r0.x, (int)r1.x, (int)r0.y, (int)r1.y); \
    uint2v r2 = __builtin_amdgcn_permlane32_swap(lo[2], lo[3], false, false); \
    uint2v r3 = __builtin_amdgcn_permlane32_swap(hi[2], hi[3], false, false); \
    ZK[1] = make_int4((int)r2.x, (int)r3.x, (int)r2.y, (int)r3.y); }

// Write ZK regs (2 int4) into state buffer WB. Conflict-free 512B runs.
#define WRITEZ(ZK, WB) { \
    (WB)[(ot * 4 + khalf) * 32 + lane31] = ZK[0]; \
    (WB)[(ot * 4 + 2 + khalf) * 32 + lane31] = ZK[1]; }

// xw extra-K term for phase PH at step T into ACC.
#define XWSTEP(PH, T, ACC) { \
    int widx_ = (PH) == 0 ? (lane31 + (T) - 1) : (lane31 + 17 - (T)); \
    const int4* p_ = (l < 32) ? (xw + widx_) : (&zc); \
    bf16x8 bx_ = __builtin_bit_cast(bf16x8, *p_); \
    ACC = MFMA32(w1x, bx_, ACC); }

// Full DP interval with GEMM, SPLIT-K dual accumulators:
//   accA: xw + even slots (2,4,..,14)   accB: self0,self1 + odd slots (3,..,15)
// -> two independent 8/9-long dep chains per wave; summed before pack.
#define INTERVAL_G(PH, T, RB, WB, ZK) { \
  bf16x8 afA[2], afB[2], afC[2]; \
  LOAD_AF(afA, 4) \
  f32x16 accA = {}, accB = {}; \
  XWSTEP(PH, T, accA) \
  __builtin_amdgcn_s_setprio(1); \
  SELFSTEP(ZK, 0, accB) SELFSTEP(ZK, 1, accB) \
  LOAD_AF(afB, 6) \
  GSTEP(RB, (2 * w + 2) & 15, w2c[2], accA) \
  GSTEP(RB, (2 * w + 3) & 15, w2c[3], accB) \
  LOAD_AF(afC, 8) \
  GSTEP(RB, (2 * w + 4) & 15, afA[0], accA) \
  GSTEP(RB, (2 * w + 5) & 15, afA[1], accB) \
  LOAD_AF(afA, 10) \
  GSTEP(RB, (2 * w + 6) & 15, afB[0], accA) \
  GSTEP(RB, (2 * w + 7) & 15, afB[1], accB) \
  LOAD_AF(afB, 12) \
  GSTEP(RB, (2 * w + 8) & 15, afC[0], accA) \
  GSTEP(RB, (2 * w + 9) & 15, afC[1], accB) \
  LOAD_AF(afC, 14) \
  GSTEP(RB, (2 * w + 10) & 15, afA[0], accA) \
  GSTEP(RB, (2 * w + 11) & 15, afA[1], accB) \
  GSTEP(RB, (2 * w + 12) & 15, afB[0], accA) \
  GSTEP(RB, (2 * w + 13) & 15, afB[1], accB) \
  GSTEP(RB, (2 * w + 14) & 15, afC[0], accA) \
  GSTEP(RB, (2 * w + 15) & 15, afC[1], accB) \
  __builtin_amdgcn_s_setprio(0); \
  f32x16 acc = accA + accB; \
  PACKZ(ZK) \
  WRITEZ(ZK, WB) }

// Peel interval (T=1): no GEMM.
#define INTERVAL_P(PH, WB, ZK) { \
  f32x16 acc = {}; \
  XWSTEP(PH, 1, acc) \
  PACKZ(ZK) \
  WRITEZ(ZK, WB) }

__global__ __launch_bounds__(512, 4)
void chain_kernel(const float* __restrict__ x, const unsigned short* __restrict__ ws,
                  float* __restrict__ out) {
  // Per-phase double-buffered state, chunk-major: buf[c*32 + r] = bf16 elems
  // [8c..8c+7] of state row r (32 rows per tile). 4 x 16KB = 64KB.
  __shared__ int4 UA[2][1024];
  __shared__ int4 UB[2][1024];
  __shared__ int4 xw[48];   // [x0,x1,x2,x3,1,0,0,0] bf16 chunks, rows j0-8 .. j0+39
  __shared__ int4 zc;

  const int tid = threadIdx.x;
  const int l = tid & 63;
  const int w = tid >> 6;        // 8 waves
  const int ot = w;              // one 32-output tile per wave
  const int lane31 = l & 31;
  const int khalf = l >> 5;
  const int tile = blockIdx.x;
  const int b = tile >> 6;
  const int j0 = (tile & 63) * 32;

  const int4* w2f = (const int4*)ws;
  const int4* w4f = (const int4*)(ws + 65536);
  const int4* w1xg = (const int4*)(ws + 131072);
  const int4* w3xg = (const int4*)(ws + 135168);

  if (tid == 0) zc = make_int4(0, 0, 0, 0);
  if (tid < 48) {
    int j = j0 - 8 + tid;
    int4 c = make_int4(0, 0, 0, 0);
    if (j >= 0 && j < 2048) {
      const float* xb = x + (b * 4) * 2048 + j;
      unsigned short h0 = f2bf(xb[0]);
      unsigned short h1 = f2bf(xb[2048]);
      unsigned short h2 = f2bf(xb[4096]);
      unsigned short h3 = f2bf(xb[6144]);
      c = make_int4((int)(h0 | ((unsigned int)h1 << 16)),
                    (int)(h2 | ((unsigned int)h3 << 16)),
                    0x00003f80, 0);  // chunk[4] = bf16(1.0) multiplies the bias row
    }
    xw[tid] = c;
  }

  // Rotated W2 cache: slot i = physical ks (2w+i)&15; slots 0,1 = SELF ks.
  bf16x8 w2c[4];
  bf16x8 w1x;
  w1x = __builtin_bit_cast(bf16x8, w1xg[ot * 64 + l]);
#pragma unroll
  for (int i = 0; i < 4; ++i) {
    int ksr = (2 * w + i) & 15;
    w2c[i] = __builtin_bit_cast(bf16x8, w2f[(ot * 16 + ksr) * 64 + l]);
  }
  __syncthreads();

  // zkU/zkD: this wave's packed state (B-frag layout), ks slots {2w, 2w+1}.
  // Lifetime: packed at pair k, LDS-written same pair, self-consumed pair k+1.
  int4 zkU[2], zkD[2];

  // ---- pair 0 (T=1): no previous state ----
  INTERVAL_P(0, UA[0], zkU)
  INTERVAL_P(1, UB[0], zkD)
  __syncthreads();

  // ---- pairs 1..7 (T=2..8): rolled loop (R19: unroll hurts I$) ----
#pragma unroll 1
  for (int k = 1; k < 8; ++k) {
    const int4* ra = UA[(k - 1) & 1];
    int4* wa = UA[k & 1];
    const int4* rb = UB[(k - 1) & 1];
    int4* wb = UB[k & 1];
    const int T = k + 1;
    INTERVAL_G(0, T, ra, wa, zkU)
    INTERVAL_G(1, T, rb, wb, zkD)
    __syncthreads();
  }

  // ---- final: miu^T = relu(W3x + b3 + 2b4 + W4*up(8) + W4*down(8)) ----
  // up(8) in UA[1] + zkU self slots; down(8) in UB[1] + zkD. Split-K here too.
  {
    f32x16 accA = {}, accB = {};
    { int widx = lane31 + 8;
      const int4* p_ = (l < 32) ? (xw + widx) : (&zc);
      bf16x8 bx = __builtin_bit_cast(bf16x8, *p_);
      bf16x8 w3x = __builtin_bit_cast(bf16x8, w3xg[ot * 64 + l]);
      accA = MFMA32(w3x, bx, accA); }
    __builtin_amdgcn_s_setprio(1);
#pragma unroll 1
    for (int ph = 0; ph < 2; ++ph) {
      const int4* Sp = ph ? UB[1] : UA[1];
      const int4* zz = ph ? zkD : zkU;
      {
        bf16x8 af0 = __builtin_bit_cast(bf16x8, w4f[(ot * 16 + 2 * w) * 64 + l]);
        bf16x8 bu0 = __builtin_bit_cast(bf16x8, zz[0]);
        accB = MFMA32(af0, bu0, accB);
        bf16x8 af1 = __builtin_bit_cast(bf16x8, w4f[(ot * 16 + 2 * w + 1) * 64 + l]);
        bf16x8 bu1 = __builtin_bit_cast(bf16x8, zz[1]);
        accA = MFMA32(af1, bu1, accA);
      }
#pragma unroll
      for (int i = 2; i < 16; i += 2) {
        int ksr0 = (2 * w + i) & 15;
        bf16x8 af0 = __builtin_bit_cast(bf16x8, w4f[(ot * 16 + ksr0) * 64 + l]);
        bf16x8 bu0 = __builtin_bit_cast(bf16x8, Sp[(2 * ksr0 + khalf) * 32 + lane31]);
        accB = MFMA32(af0, bu0, accB);
        int ksr1 = (2 * w + i + 1) & 15;
        bf16x8 af1 = __builtin_bit_cast(bf16x8, w4f[(ot * 16 + ksr1) * 64 + l]);
        bf16x8 bu1 = __builtin_bit_cast(bf16x8, Sp[(2 * ksr1 + khalf) * 32 + lane31]);
        accA = MFMA32(af1, bu1, accA);
      }
    }
    __builtin_amdgcn_s_setprio(0);
    f32x16 acc = accA + accB;
    int pbase = (b * 2048 + j0 + lane31) * 256;
#pragma unroll
    for (int q = 0; q < 4; ++q) {
      int ob = ot * 32 + 8 * q + 4 * khalf;
      float4 v;
      v.x = fmaxf(acc[4 * q + 0], 0.0f);
      v.y = fmaxf(acc[4 * q + 1], 0.0f);
      v.z = fmaxf(acc[4 * q + 2], 0.0f);
      v.w = fmaxf(acc[4 * q + 3], 0.0f);
      *(float4*)(out + pbase + ob) = v;
    }
  }
}

extern "C" void kernel_launch(void* const* d_in, const int* in_sizes, int n_in,
                              void* d_out, int out_size, void* d_ws, size_t ws_size,
                              hipStream_t stream) {
  const float* x  = (const float*)d_in[0];
  const float* W1 = (const float*)d_in[1];
  const float* b1 = (const float*)d_in[2];
  const float* W2 = (const float*)d_in[3];
  const float* b2 = (const float*)d_in[4];
  const float* W3 = (const float*)d_in[5];
  const float* b3 = (const float*)d_in[6];
  const float* W4 = (const float*)d_in[7];
  const float* b4 = (const float*)d_in[8];
  unsigned short* ws = (unsigned short*)d_ws;

  prep_kernel<<<68, 256, 0, stream>>>(W1, b1, W2, b2, W3, b3, W4, b4, ws);
  chain_kernel<<<1024, 512, 0, stream>>>(x, ws, (float*)d_out);
}

// Round 13
// 135.569 us; speedup vs baseline: 1.6476x; 1.4840x over previous
//
#include <hip/hip_runtime.h>

// BahdanauAttention_16518444220431 — diagonal-DP recurrence on MI355X (gfx950).
// R23 = R17 EXACT (verified 59.4us chain, best) + SPLIT-K DUAL ACC CHAINS.
// R22 lesson: the 512-thr/launch_bounds(512,4) config has an effective
// 64-VGPR wall (R20 fits@64, R21/R22 spill at 64+eps with VGPR_Count pinned
// 64) — split-K was never tested there, it was strangled by geometry. R17's
// (256,2) config allocates 124 with ~60 headroom (R11: ~250-reg peaks OK).
// Dep-latency theory (unfalsified): R17 and R20 both = 4 acc chains/SIMD,
// both ~52% MfmaUtil, same wall => MFMA dependent-issue latency L~250cyc,
// util ~= chains*32.3/L. Fix: split each interval's 17-MFMA chain by ks
// parity into accA (xw+self1,3+even = 9) / accB (self0,2+odd = 8), one
// vector add before pack. Chains/SIMD 4->8. Accs are INTRA-interval liveness
// only (unlike the 4 spilled cross-section prefetch attempts R12/13/18/21).
// Same split in final GEMM. All else byte-identical to R17.
// CLOSED: cross-section reg state (4 spills), fused write (R15 race),
// stagger (R16), unroll (R19 I$), occupancy (R20), 512-thr geometry (64 wall).
// PROVEN: self-ks (R17 +10%), vectorized prep, ~70us harness floor.
// Tripwire: FETCH>10MB = spill -> revert R17 verbatim as final.

typedef __bf16 bf16x8 __attribute__((ext_vector_type(8)));
typedef __bf16 bf16x4 __attribute__((ext_vector_type(4)));
typedef float f32x16 __attribute__((ext_vector_type(16)));
typedef unsigned int uint2v __attribute__((ext_vector_type(2)));

#define MFMA32(a, b, c) __builtin_amdgcn_mfma_f32_32x32x16_bf16(a, b, c, 0, 0, 0)

__device__ __forceinline__ unsigned short f2bf(float f) {
  unsigned int u = __builtin_bit_cast(unsigned int, f);
  u += 0x7fffu + ((u >> 16) & 1u);
  return (unsigned short)(u >> 16);
}

__device__ __forceinline__ unsigned pk2(float a, float b) {
  return (unsigned)f2bf(a) | ((unsigned)f2bf(b) << 16);
}

// ws layout (bf16 elements):
//   [0,65536)        W2 fragments: ((ot*16+ks)*64+lane)*8+j ; o=ot*32+(lane&31), k=ks*16+(lane>>5)*8+j
//   [65536,131072)   W4 fragments, same permutation
//   [131072,135168)  W1-extra frags: lanes<32: j<4 -> W1[o][j], j==4 -> b1[o]+b2[o], else 0
//   [135168,139264)  W3-extra frags: j==4 -> b3[o]+2*b4[o]
__global__ void prep_kernel(const float* __restrict__ W1, const float* __restrict__ b1,
                            const float* __restrict__ W2, const float* __restrict__ b2,
                            const float* __restrict__ W3, const float* __restrict__ b3,
                            const float* __restrict__ W4, const float* __restrict__ b4,
                            unsigned short* __restrict__ ws) {
  int t8 = blockIdx.x * 256 + threadIdx.x;
  if (t8 >= 17408) return;   // 139264 / 8
  int idx = t8 * 8;
  int4 outv;
  if (idx < 131072) {
    const float* W = (idx < 65536) ? W2 : W4;
    int f = (idx & 65535) >> 3;
    int lane = f & 63, slot = f >> 6;
    int ks = slot & 15, ot = slot >> 4;
    int o = ot * 32 + (lane & 31);
    int kbase = ks * 16 + (lane >> 5) * 8;
    const float4* row = (const float4*)(W + o * 256 + kbase);
    float4 v0 = row[0];
    float4 v1 = row[1];
    outv = make_int4((int)pk2(v0.x, v0.y), (int)pk2(v0.z, v0.w),
                     (int)pk2(v1.x, v1.y), (int)pk2(v1.z, v1.w));
  } else {
    int i = idx - 131072;
    bool first = (i < 4096);
    int f = (i & 4095) >> 3;
    int lane = f & 63, ot = f >> 6;
    int o = ot * 32 + (lane & 31);
    outv = make_int4(0, 0, 0, 0);
    if (lane < 32) {
      const float4 wrow = *(const float4*)((first ? W1 : W3) + o * 4);
      float bias = first ? (b1[o] + b2[o]) : (b3[o] + 2.0f * b4[o]);
      outv = make_int4((int)pk2(wrow.x, wrow.y), (int)pk2(wrow.z, wrow.w),
                       (int)pk2(bias, 0.0f), 0);
    }
  }
  *(int4*)(ws + idx) = outv;
}

#define NC 10  // W2 slots cached (0..3 = self ks); slots 10..15 streamed per GEMM

// Load 2 afs slots (physical ks rotated by 4w) into AF[0..1][ot].
#define LOAD_AF(AF, S0) { \
    int ka_ = (4 * w + NC + (S0)) & 15; \
    AF[0][0] = __builtin_bit_cast(bf16x8, w2f[(ot0 * 16 + ka_) * 64 + l]); \
    AF[0][1] = __builtin_bit_cast(bf16x8, w2f[((ot0 + 1) * 16 + ka_) * 64 + l]); \
    int kb_ = (4 * w + NC + (S0) + 1) & 15; \
    AF[1][0] = __builtin_bit_cast(bf16x8, w2f[(ot0 * 16 + kb_) * 64 + l]); \
    AF[1][1] = __builtin_bit_cast(bf16x8, w2f[((ot0 + 1) * 16 + kb_) * 64 + l]); }

// One LDS-sourced K-slice into chain ACC: 1 ds_read_b128 feeds 2 MFMAs.
#define GSTEP(RB, KSR, A0, A1, ACC) { \
    bf16x8 bu_ = __builtin_bit_cast(bf16x8, (RB)[(2 * (KSR) + khalf) * 32 + lane31]); \
    ACC[0] = MFMA32(A0, bu_, ACC[0]); \
    ACC[1] = MFMA32(A1, bu_, ACC[1]); }

// Self K-slice from zk registers (zero LDS dependency) into chain ACC.
#define SELFSTEP(ZK, S, ACC) { \
    bf16x8 bu_ = __builtin_bit_cast(bf16x8, ZK[(S) >> 1][(S) & 1]); \
    ACC[0] = MFMA32(w2c[0][S], bu_, ACC[0]); \
    ACC[1] = MFMA32(w2c[1][S], bu_, ACC[1]); }

// relu + bf16 pack + permlane32_swap into full-int4 B-frag form -> ZK regs.
// ZK[t2][p] = chunk (ot0+t2)*4 + 2p + khalf, row lane31.
#define PACKZ(ZK) { \
    _Pragma("unroll") for (int t2 = 0; t2 < 2; ++t2) { \
      unsigned lo[4], hi[4]; \
      _Pragma("unroll") for (int q = 0; q < 4; ++q) { \
        bf16x4 h; \
        h.x = (__bf16)fmaxf(acc[t2][4 * q + 0], 0.0f); \
        h.y = (__bf16)fmaxf(acc[t2][4 * q + 1], 0.0f); \
        h.z = (__bf16)fmaxf(acc[t2][4 * q + 2], 0.0f); \
        h.w = (__bf16)fmaxf(acc[t2][4 * q + 3], 0.0f); \
        uint2 u = __builtin_bit_cast(uint2, h); \
        lo[q] = u.x; hi[q] = u.y; \
      } \
      uint2v r0 = __builtin_amdgcn_permlane32_swap(lo[0], lo[1], false, false); \
      uint2v r1 = __builtin_amdgcn_permlane32_swap(hi[0], hi[1], false, false); \
      ZK[t2][0] = make_int4((int)r0.x, (int)r1.x, (int)r0.y, (int)r1.y); \
      uint2v r2 = __builtin_amdgcn_permlane32_swap(lo[2], lo[3], false, false); \
      uint2v r3 = __builtin_amdgcn_permlane32_swap(hi[2], hi[3], false, false); \
      ZK[t2][1] = make_int4((int)r2.x, (int)r3.x, (int)r2.y, (int)r3.y); \
    } }

// Write ZK regs (4 int4) into state buffer WB. Conflict-free 512B runs.
#define WRITEZ(ZK, WB) { \
    _Pragma("unroll") for (int t2 = 0; t2 < 2; ++t2) \
    _Pragma("unroll") for (int p = 0; p < 2; ++p) \
      (WB)[((ot0 + t2) * 4 + 2 * p + khalf) * 32 + lane31] = ZK[t2][p]; }

// xw extra-K term for phase PH at step T into chain ACC.
#define XWSTEP(PH, T, ACC) { \
    int widx_ = (PH) == 0 ? (lane31 + (T) - 1) : (lane31 + 17 - (T)); \
    const int4* p_ = (l < 32) ? (xw + widx_) : (&zc); \
    bf16x8 bx_ = __builtin_bit_cast(bf16x8, *p_); \
    ACC[0] = MFMA32(w1x[0], bx_, ACC[0]); \
    ACC[1] = MFMA32(w1x[1], bx_, ACC[1]); }

// Full DP interval with GEMM, SPLIT-K: chain A = xw + self1,3 + even-streamed
// slots (9 links); chain B = self0,2 + odd-streamed slots (8 links). Summed
// once before pack. Structure otherwise identical to R17.
#define INTERVAL_G(PH, T, RB, WB, ZK) { \
  bf16x8 afA[2][2], afB[2][2], afC[2][2]; \
  LOAD_AF(afA, 0) \
  f32x16 accA[2] = {}, accB[2] = {}; \
  XWSTEP(PH, T, accA) \
  __builtin_amdgcn_s_setprio(1); \
  SELFSTEP(ZK, 0, accB) SELFSTEP(ZK, 1, accA) \
  SELFSTEP(ZK, 2, accB) SELFSTEP(ZK, 3, accA) \
  LOAD_AF(afB, 2) \
  GSTEP(RB, (4 * w + 4) & 15, w2c[0][4], w2c[1][4], accB) \
  GSTEP(RB, (4 * w + 5) & 15, w2c[0][5], w2c[1][5], accA) \
  GSTEP(RB, (4 * w + 6) & 15, w2c[0][6], w2c[1][6], accB) \
  GSTEP(RB, (4 * w + 7) & 15, w2c[0][7], w2c[1][7], accA) \
  GSTEP(RB, (4 * w + 8) & 15, w2c[0][8], w2c[1][8], accB) \
  GSTEP(RB, (4 * w + 9) & 15, w2c[0][9], w2c[1][9], accA) \
  GSTEP(RB, (4 * w + 10) & 15, afA[0][0], afA[0][1], accB) \
  GSTEP(RB, (4 * w + 11) & 15, afA[1][0], afA[1][1], accA) \
  LOAD_AF(afC, 4) \
  GSTEP(RB, (4 * w + 12) & 15, afB[0][0], afB[0][1], accB) \
  GSTEP(RB, (4 * w + 13) & 15, afB[1][0], afB[1][1], accA) \
  GSTEP(RB, (4 * w + 14) & 15, afC[0][0], afC[0][1], accB) \
  GSTEP(RB, (4 * w + 15) & 15, afC[1][0], afC[1][1], accA) \
  __builtin_amdgcn_s_setprio(0); \
  f32x16 acc[2] = {accA[0] + accB[0], accA[1] + accB[1]}; \
  PACKZ(ZK) \
  WRITEZ(ZK, WB) }

// Peel interval (T=1): no GEMM.
#define INTERVAL_P(PH, WB, ZK) { \
  f32x16 acc[2] = {}; \
  XWSTEP(PH, 1, acc) \
  PACKZ(ZK) \
  WRITEZ(ZK, WB) }

__global__ __launch_bounds__(256, 2)
void chain_kernel(const float* __restrict__ x, const unsigned short* __restrict__ ws,
                  float* __restrict__ out) {
  // Per-phase double-buffered state, chunk-major: buf[c*32 + r] = bf16 elems
  // [8c..8c+7] of state row r (32 rows per tile). 4 x 16KB = 64KB.
  __shared__ int4 UA[2][1024];
  __shared__ int4 UB[2][1024];
  __shared__ int4 xw[48];   // [x0,x1,x2,x3,1,0,0,0] bf16 chunks, rows j0-8 .. j0+39
  __shared__ int4 zc;

  const int tid = threadIdx.x;
  const int l = tid & 63;
  const int w = tid >> 6;
  const int lane31 = l & 31;
  const int khalf = l >> 5;
  const int tile = blockIdx.x;
  const int b = tile >> 6;
  const int j0 = (tile & 63) * 32;

  const int4* w2f = (const int4*)ws;
  const int4* w4f = (const int4*)(ws + 65536);
  const int4* w1xg = (const int4*)(ws + 131072);
  const int4* w3xg = (const int4*)(ws + 135168);

  if (tid == 0) zc = make_int4(0, 0, 0, 0);
  if (tid < 48) {
    int j = j0 - 8 + tid;
    int4 c = make_int4(0, 0, 0, 0);
    if (j >= 0 && j < 2048) {
      const float* xb = x + (b * 4) * 2048 + j;
      unsigned short h0 = f2bf(xb[0]);
      unsigned short h1 = f2bf(xb[2048]);
      unsigned short h2 = f2bf(xb[4096]);
      unsigned short h3 = f2bf(xb[6144]);
      c = make_int4((int)(h0 | ((unsigned int)h1 << 16)),
                    (int)(h2 | ((unsigned int)h3 << 16)),
                    0x00003f80, 0);  // chunk[4] = bf16(1.0) multiplies the bias row
    }
    xw[tid] = c;
  }

  const int ot0 = w * 2;
  // Rotated W2 cache: slot i = physical ks (4w+i)&15; slots 0..3 are this
  // wave's SELF ks (matching its own zk chunks) at compile-time indices.
  bf16x8 w2c[2][NC];
  bf16x8 w1x[2];
#pragma unroll
  for (int t2 = 0; t2 < 2; ++t2) {
    w1x[t2] = __builtin_bit_cast(bf16x8, w1xg[(ot0 + t2) * 64 + l]);
#pragma unroll
    for (int i = 0; i < NC; ++i) {
      int ksr = (4 * w + i) & 15;
      w2c[t2][i] = __builtin_bit_cast(bf16x8, w2f[((ot0 + t2) * 16 + ksr) * 64 + l]);
    }
  }
  __syncthreads();

  // zkU/zkD: this wave's packed state (B-frag layout), ks slots [4w,4w+4).
  // Lifetime: packed at pair k, LDS-written same pair, self-consumed pair k+1.
  int4 zkU[2][2], zkD[2][2];

  // ---- pair 0 (T=1): no previous state ----
  INTERVAL_P(0, UA[0], zkU)
  INTERVAL_P(1, UB[0], zkD)
  __syncthreads();

  // ---- pairs 1..7 (T=2..8): rolled loop, one barrier per pair ----
#pragma unroll 1
  for (int k = 1; k < 8; ++k) {
    const int4* ra = UA[(k - 1) & 1];
    int4* wa = UA[k & 1];
    const int4* rb = UB[(k - 1) & 1];
    int4* wb = UB[k & 1];
    const int T = k + 1;
    INTERVAL_G(0, T, ra, wa, zkU)
    INTERVAL_G(1, T, rb, wb, zkD)
    __syncthreads();
  }

  // ---- final: miu^T = relu(W3x + b3 + 2b4 + W4*up(8) + W4*down(8)) ----
  // up(8) in UA[1] + zkU self slots; down(8) in UB[1] + zkD. Split-K too.
  {
    f32x16 accA[2] = {}, accB[2] = {};
    { int widx = lane31 + 8;
      const int4* p_ = (l < 32) ? (xw + widx) : (&zc);
      bf16x8 bx = __builtin_bit_cast(bf16x8, *p_);
      bf16x8 w3x0 = __builtin_bit_cast(bf16x8, w3xg[ot0 * 64 + l]);
      bf16x8 w3x1 = __builtin_bit_cast(bf16x8, w3xg[(ot0 + 1) * 64 + l]);
      accA[0] = MFMA32(w3x0, bx, accA[0]);
      accA[1] = MFMA32(w3x1, bx, accA[1]); }
    __builtin_amdgcn_s_setprio(1);
#pragma unroll 1
    for (int ph = 0; ph < 2; ++ph) {
      const int4* Sp = ph ? UB[1] : UA[1];
      const int4* zz = ph ? &zkD[0][0] : &zkU[0][0];
#pragma unroll
      for (int s = 0; s < 4; ++s) {
        int ksr = 4 * w + s;
        bf16x8 af0 = __builtin_bit_cast(bf16x8, w4f[(ot0 * 16 + ksr) * 64 + l]);
        bf16x8 af1 = __builtin_bit_cast(bf16x8, w4f[((ot0 + 1) * 16 + ksr) * 64 + l]);
        bf16x8 bu = __builtin_bit_cast(bf16x8, zz[s]);
        if (s & 1) { accA[0] = MFMA32(af0, bu, accA[0]); accA[1] = MFMA32(af1, bu, accA[1]); }
        else       { accB[0] = MFMA32(af0, bu, accB[0]); accB[1] = MFMA32(af1, bu, accB[1]); }
      }
#pragma unroll
      for (int i = 4; i < 16; ++i) {
        int ksr = (4 * w + i) & 15;
        bf16x8 af0 = __builtin_bit_cast(bf16x8, w4f[(ot0 * 16 + ksr) * 64 + l]);
        bf16x8 af1 = __builtin_bit_cast(bf16x8, w4f[((ot0 + 1) * 16 + ksr) * 64 + l]);
        bf16x8 bu = __builtin_bit_cast(bf16x8, Sp[(2 * ksr + khalf) * 32 + lane31]);
        if (i & 1) { accA[0] = MFMA32(af0, bu, accA[0]); accA[1] = MFMA32(af1, bu, accA[1]); }
        else       { accB[0] = MFMA32(af0, bu, accB[0]); accB[1] = MFMA32(af1, bu, accB[1]); }
      }
    }
    __builtin_amdgcn_s_setprio(0);
    f32x16 acc[2] = {accA[0] + accB[0], accA[1] + accB[1]};
    int pbase = (b * 2048 + j0 + lane31) * 256;
#pragma unroll
    for (int t2 = 0; t2 < 2; ++t2) {
#pragma unroll
      for (int q = 0; q < 4; ++q) {
        int ob = (ot0 + t2) * 32 + 8 * q + 4 * khalf;
        float4 v;
        v.x = fmaxf(acc[t2][4 * q + 0], 0.0f);
        v.y = fmaxf(acc[t2][4 * q + 1], 0.0f);
        v.z = fmaxf(acc[t2][4 * q + 2], 0.0f);
        v.w = fmaxf(acc[t2][4 * q + 3], 0.0f);
        *(float4*)(out + pbase + ob) = v;
      }
    }
  }
}

extern "C" void kernel_launch(void* const* d_in, const int* in_sizes, int n_in,
                              void* d_out, int out_size, void* d_ws, size_t ws_size,
                              hipStream_t stream) {
  const float* x  = (const float*)d_in[0];
  const float* W1 = (const float*)d_in[1];
  const float* b1 = (const float*)d_in[2];
  const float* W2 = (const float*)d_in[3];
  const float* b2 = (const float*)d_in[4];
  const float* W3 = (const float*)d_in[5];
  const float* b3 = (const float*)d_in[6];
  const float* W4 = (const float*)d_in[7];
  const float* b4 = (const float*)d_in[8];
  unsigned short* ws = (unsigned short*)d_ws;

  prep_kernel<<<68, 256, 0, stream>>>(W1, b1, W2, b2, W3, b3, W4, b4, ws);
  chain_kernel<<<1024, 256, 0, stream>>>(x, ws, (float*)d_out);
}

// Round 14
// 127.521 us; speedup vs baseline: 1.7515x; 1.0631x over previous
//
#include <hip/hip_runtime.h>

// BahdanauAttention_16518444220431 — diagonal-DP recurrence on MI355X (gfx950).
// R24 = R17 VERBATIM (the session's verified best: dur 129.5us, chain 59.4us,
// VGPR 124, FETCH 1.9MB, absmax 0.015625). Final consolidation round.
// SESSION LEDGER (13 rounds): ONE real win — R17's self-ks + pair structure
// + vectorized prep (131.3->129.5 total; chain 65.5->59.4; MfmaUtil 47->53,
// predicted & verified). Neutral: LDS-conflict elimination (R11, 2.1e6->0),
// setprio (R11), barrier halving (R14), block stagger (R16), occupancy
// doubling (R20: 17->34%, wall unmoved). Infeasible: register expansion of
// ANY kind spills — cross-phase/cross-interval prefetch (R12/R13/R18/R21),
// split-K dual acc (R22 at 64-wall, R23 at unified VGPR+AGPR budget);
// fused-pair write races (R15); full unroll blows I$ (R19: 59->73us).
// CEILING ANALYSIS: MFMA dense floor ~29us; wall 59.4 = MFMA (53% util) +
// LDS pipe (~49% busy) with near-zero overlap forced by the 1:1 ds_read->
// MFMA dependency; breaking it needs registers the unified file doesn't
// have. Structure is at its measured multi-axis optimum.

typedef __bf16 bf16x8 __attribute__((ext_vector_type(8)));
typedef __bf16 bf16x4 __attribute__((ext_vector_type(4)));
typedef float f32x16 __attribute__((ext_vector_type(16)));
typedef unsigned int uint2v __attribute__((ext_vector_type(2)));

#define MFMA32(a, b, c) __builtin_amdgcn_mfma_f32_32x32x16_bf16(a, b, c, 0, 0, 0)

__device__ __forceinline__ unsigned short f2bf(float f) {
  unsigned int u = __builtin_bit_cast(unsigned int, f);
  u += 0x7fffu + ((u >> 16) & 1u);
  return (unsigned short)(u >> 16);
}

__device__ __forceinline__ unsigned pk2(float a, float b) {
  return (unsigned)f2bf(a) | ((unsigned)f2bf(b) << 16);
}

// ws layout (bf16 elements):
//   [0,65536)        W2 fragments: ((ot*16+ks)*64+lane)*8+j ; o=ot*32+(lane&31), k=ks*16+(lane>>5)*8+j
//   [65536,131072)   W4 fragments, same permutation
//   [131072,135168)  W1-extra frags: lanes<32: j<4 -> W1[o][j], j==4 -> b1[o]+b2[o], else 0
//   [135168,139264)  W3-extra frags: j==4 -> b3[o]+2*b4[o]
__global__ void prep_kernel(const float* __restrict__ W1, const float* __restrict__ b1,
                            const float* __restrict__ W2, const float* __restrict__ b2,
                            const float* __restrict__ W3, const float* __restrict__ b3,
                            const float* __restrict__ W4, const float* __restrict__ b4,
                            unsigned short* __restrict__ ws) {
  int t8 = blockIdx.x * 256 + threadIdx.x;
  if (t8 >= 17408) return;   // 139264 / 8
  int idx = t8 * 8;
  int4 outv;
  if (idx < 131072) {
    const float* W = (idx < 65536) ? W2 : W4;
    int f = (idx & 65535) >> 3;
    int lane = f & 63, slot = f >> 6;
    int ks = slot & 15, ot = slot >> 4;
    int o = ot * 32 + (lane & 31);
    int kbase = ks * 16 + (lane >> 5) * 8;
    const float4* row = (const float4*)(W + o * 256 + kbase);
    float4 v0 = row[0];
    float4 v1 = row[1];
    outv = make_int4((int)pk2(v0.x, v0.y), (int)pk2(v0.z, v0.w),
                     (int)pk2(v1.x, v1.y), (int)pk2(v1.z, v1.w));
  } else {
    int i = idx - 131072;
    bool first = (i < 4096);
    int f = (i & 4095) >> 3;
    int lane = f & 63, ot = f >> 6;
    int o = ot * 32 + (lane & 31);
    outv = make_int4(0, 0, 0, 0);
    if (lane < 32) {
      const float4 wrow = *(const float4*)((first ? W1 : W3) + o * 4);
      float bias = first ? (b1[o] + b2[o]) : (b3[o] + 2.0f * b4[o]);
      outv = make_int4((int)pk2(wrow.x, wrow.y), (int)pk2(wrow.z, wrow.w),
                       (int)pk2(bias, 0.0f), 0);
    }
  }
  *(int4*)(ws + idx) = outv;
}

#define NC 10  // W2 slots cached (0..3 = self ks); slots 10..15 streamed per GEMM

// Load 2 afs slots (physical ks rotated by 4w) into AF[0..1][ot].
#define LOAD_AF(AF, S0) { \
    int ka_ = (4 * w + NC + (S0)) & 15; \
    AF[0][0] = __builtin_bit_cast(bf16x8, w2f[(ot0 * 16 + ka_) * 64 + l]); \
    AF[0][1] = __builtin_bit_cast(bf16x8, w2f[((ot0 + 1) * 16 + ka_) * 64 + l]); \
    int kb_ = (4 * w + NC + (S0) + 1) & 15; \
    AF[1][0] = __builtin_bit_cast(bf16x8, w2f[(ot0 * 16 + kb_) * 64 + l]); \
    AF[1][1] = __builtin_bit_cast(bf16x8, w2f[((ot0 + 1) * 16 + kb_) * 64 + l]); }

// One LDS-sourced K-slice: 1 ds_read_b128 feeds 2 MFMAs. KSR runtime (addr only).
#define GSTEP(RB, KSR, A0, A1) { \
    bf16x8 bu_ = __builtin_bit_cast(bf16x8, (RB)[(2 * (KSR) + khalf) * 32 + lane31]); \
    acc[0] = MFMA32(A0, bu_, acc[0]); \
    acc[1] = MFMA32(A1, bu_, acc[1]); }

// Self K-slice from zk registers (zero LDS dependency). S literal 0..3.
#define SELFSTEP(ZK, S) { \
    bf16x8 bu_ = __builtin_bit_cast(bf16x8, ZK[(S) >> 1][(S) & 1]); \
    acc[0] = MFMA32(w2c[0][S], bu_, acc[0]); \
    acc[1] = MFMA32(w2c[1][S], bu_, acc[1]); }

// relu + bf16 pack + permlane32_swap into full-int4 B-frag form -> ZK regs.
// ZK[t2][p] = chunk (ot0+t2)*4 + 2p + khalf, row lane31.
#define PACKZ(ZK) { \
    _Pragma("unroll") for (int t2 = 0; t2 < 2; ++t2) { \
      unsigned lo[4], hi[4]; \
      _Pragma("unroll") for (int q = 0; q < 4; ++q) { \
        bf16x4 h; \
        h.x = (__bf16)fmaxf(acc[t2][4 * q + 0], 0.0f); \
        h.y = (__bf16)fmaxf(acc[t2][4 * q + 1], 0.0f); \
        h.z = (__bf16)fmaxf(acc[t2][4 * q + 2], 0.0f); \
        h.w = (__bf16)fmaxf(acc[t2][4 * q + 3], 0.0f); \
        uint2 u = __builtin_bit_cast(uint2, h); \
        lo[q] = u.x; hi[q] = u.y; \
      } \
      uint2v r0 = __builtin_amdgcn_permlane32_swap(lo[0], lo[1], false, false); \
      uint2v r1 = __builtin_amdgcn_permlane32_swap(hi[0], hi[1], false, false); \
      ZK[t2][0] = make_int4((int)r0.x, (int)r1.x, (int)r0.y, (int)r1.y); \
      uint2v r2 = __builtin_amdgcn_permlane32_swap(lo[2], lo[3], false, false); \
      uint2v r3 = __builtin_amdgcn_permlane32_swap(hi[2], hi[3], false, false); \
      ZK[t2][1] = make_int4((int)r2.x, (int)r3.x, (int)r2.y, (int)r3.y); \
    } }

// Write ZK regs (4 int4) into state buffer WB. Conflict-free 512B runs.
#define WRITEZ(ZK, WB) { \
    _Pragma("unroll") for (int t2 = 0; t2 < 2; ++t2) \
    _Pragma("unroll") for (int p = 0; p < 2; ++p) \
      (WB)[((ot0 + t2) * 4 + 2 * p + khalf) * 32 + lane31] = ZK[t2][p]; }

// xw extra-K term for phase PH at step T.
#define XWSTEP(PH, T) { \
    int widx_ = (PH) == 0 ? (lane31 + (T) - 1) : (lane31 + 17 - (T)); \
    const int4* p_ = (l < 32) ? (xw + widx_) : (&zc); \
    bf16x8 bx_ = __builtin_bit_cast(bf16x8, *p_); \
    acc[0] = MFMA32(w1x[0], bx_, acc[0]); \
    acc[1] = MFMA32(w1x[1], bx_, acc[1]); }

// Full DP interval with GEMM: self ks 0..3 from ZK (state T-1), ks 4..15
// cached/streamed, then ZK := state T (packed) and written to WB.
#define INTERVAL_G(PH, T, RB, WB, ZK) { \
  bf16x8 afA[2][2], afB[2][2], afC[2][2]; \
  LOAD_AF(afA, 0) \
  f32x16 acc[2] = {}; \
  XWSTEP(PH, T) \
  __builtin_amdgcn_s_setprio(1); \
  SELFSTEP(ZK, 0) SELFSTEP(ZK, 1) SELFSTEP(ZK, 2) SELFSTEP(ZK, 3) \
  LOAD_AF(afB, 2) \
  GSTEP(RB, (4 * w + 4) & 15, w2c[0][4], w2c[1][4]) \
  GSTEP(RB, (4 * w + 5) & 15, w2c[0][5], w2c[1][5]) \
  GSTEP(RB, (4 * w + 6) & 15, w2c[0][6], w2c[1][6]) \
  GSTEP(RB, (4 * w + 7) & 15, w2c[0][7], w2c[1][7]) \
  GSTEP(RB, (4 * w + 8) & 15, w2c[0][8], w2c[1][8]) \
  GSTEP(RB, (4 * w + 9) & 15, w2c[0][9], w2c[1][9]) \
  GSTEP(RB, (4 * w + 10) & 15, afA[0][0], afA[0][1]) \
  GSTEP(RB, (4 * w + 11) & 15, afA[1][0], afA[1][1]) \
  LOAD_AF(afC, 4) \
  GSTEP(RB, (4 * w + 12) & 15, afB[0][0], afB[0][1]) \
  GSTEP(RB, (4 * w + 13) & 15, afB[1][0], afB[1][1]) \
  GSTEP(RB, (4 * w + 14) & 15, afC[0][0], afC[0][1]) \
  GSTEP(RB, (4 * w + 15) & 15, afC[1][0], afC[1][1]) \
  __builtin_amdgcn_s_setprio(0); \
  PACKZ(ZK) \
  WRITEZ(ZK, WB) }

// Peel interval (T=1): no GEMM.
#define INTERVAL_P(PH, WB, ZK) { \
  f32x16 acc[2] = {}; \
  XWSTEP(PH, 1) \
  PACKZ(ZK) \
  WRITEZ(ZK, WB) }

__global__ __launch_bounds__(256, 2)
void chain_kernel(const float* __restrict__ x, const unsigned short* __restrict__ ws,
                  float* __restrict__ out) {
  // Per-phase double-buffered state, chunk-major: buf[c*32 + r] = bf16 elems
  // [8c..8c+7] of state row r (32 rows per tile). 4 x 16KB = 64KB.
  __shared__ int4 UA[2][1024];
  __shared__ int4 UB[2][1024];
  __shared__ int4 xw[48];   // [x0,x1,x2,x3,1,0,0,0] bf16 chunks, rows j0-8 .. j0+39
  __shared__ int4 zc;

  const int tid = threadIdx.x;
  const int l = tid & 63;
  const int w = tid >> 6;
  const int lane31 = l & 31;
  const int khalf = l >> 5;
  const int tile = blockIdx.x;
  const int b = tile >> 6;
  const int j0 = (tile & 63) * 32;

  const int4* w2f = (const int4*)ws;
  const int4* w4f = (const int4*)(ws + 65536);
  const int4* w1xg = (const int4*)(ws + 131072);
  const int4* w3xg = (const int4*)(ws + 135168);

  if (tid == 0) zc = make_int4(0, 0, 0, 0);
  if (tid < 48) {
    int j = j0 - 8 + tid;
    int4 c = make_int4(0, 0, 0, 0);
    if (j >= 0 && j < 2048) {
      const float* xb = x + (b * 4) * 2048 + j;
      unsigned short h0 = f2bf(xb[0]);
      unsigned short h1 = f2bf(xb[2048]);
      unsigned short h2 = f2bf(xb[4096]);
      unsigned short h3 = f2bf(xb[6144]);
      c = make_int4((int)(h0 | ((unsigned int)h1 << 16)),
                    (int)(h2 | ((unsigned int)h3 << 16)),
                    0x00003f80, 0);  // chunk[4] = bf16(1.0) multiplies the bias row
    }
    xw[tid] = c;
  }

  const int ot0 = w * 2;
  // Rotated W2 cache: slot i = physical ks (4w+i)&15; slots 0..3 are this
  // wave's SELF ks (matching its own zk chunks) at compile-time indices.
  bf16x8 w2c[2][NC];
  bf16x8 w1x[2];
#pragma unroll
  for (int t2 = 0; t2 < 2; ++t2) {
    w1x[t2] = __builtin_bit_cast(bf16x8, w1xg[(ot0 + t2) * 64 + l]);
#pragma unroll
    for (int i = 0; i < NC; ++i) {
      int ksr = (4 * w + i) & 15;
      w2c[t2][i] = __builtin_bit_cast(bf16x8, w2f[((ot0 + t2) * 16 + ksr) * 64 + l]);
    }
  }
  __syncthreads();

  // zkU/zkD: this wave's packed state (B-frag layout), ks slots [4w,4w+4).
  // Lifetime: packed at pair k, LDS-written same pair, self-consumed pair k+1.
  int4 zkU[2][2], zkD[2][2];

  // ---- pair 0 (T=1): no previous state ----
  INTERVAL_P(0, UA[0], zkU)
  INTERVAL_P(1, UB[0], zkD)
  __syncthreads();

  // ---- pairs 1..7 (T=2..8): one barrier per pair ----
#pragma unroll 1
  for (int k = 1; k < 8; ++k) {
    const int4* ra = UA[(k - 1) & 1];
    int4* wa = UA[k & 1];
    const int4* rb = UB[(k - 1) & 1];
    int4* wb = UB[k & 1];
    const int T = k + 1;
    INTERVAL_G(0, T, ra, wa, zkU)
    INTERVAL_G(1, T, rb, wb, zkD)
    __syncthreads();
  }

  // ---- final: miu^T = relu(W3x + b3 + 2b4 + W4*up(8) + W4*down(8)) ----
  // up(8) in UA[1] + zkU self slots; down(8) in UB[1] + zkD.
  {
    f32x16 acc[2] = {};
    { int widx = lane31 + 8;
      const int4* p_ = (l < 32) ? (xw + widx) : (&zc);
      bf16x8 bx = __builtin_bit_cast(bf16x8, *p_);
      bf16x8 w3x0 = __builtin_bit_cast(bf16x8, w3xg[ot0 * 64 + l]);
      bf16x8 w3x1 = __builtin_bit_cast(bf16x8, w3xg[(ot0 + 1) * 64 + l]);
      acc[0] = MFMA32(w3x0, bx, acc[0]);
      acc[1] = MFMA32(w3x1, bx, acc[1]); }
    __builtin_amdgcn_s_setprio(1);
#pragma unroll 1
    for (int ph = 0; ph < 2; ++ph) {
      const int4* Sp = ph ? UB[1] : UA[1];
      const int4* zz = ph ? &zkD[0][0] : &zkU[0][0];
#pragma unroll
      for (int s = 0; s < 4; ++s) {
        int ksr = 4 * w + s;
        bf16x8 af0 = __builtin_bit_cast(bf16x8, w4f[(ot0 * 16 + ksr) * 64 + l]);
        bf16x8 af1 = __builtin_bit_cast(bf16x8, w4f[((ot0 + 1) * 16 + ksr) * 64 + l]);
        bf16x8 bu = __builtin_bit_cast(bf16x8, zz[s]);
        acc[0] = MFMA32(af0, bu, acc[0]);
        acc[1] = MFMA32(af1, bu, acc[1]);
      }
#pragma unroll
      for (int i = 4; i < 16; ++i) {
        int ksr = (4 * w + i) & 15;
        bf16x8 af0 = __builtin_bit_cast(bf16x8, w4f[(ot0 * 16 + ksr) * 64 + l]);
        bf16x8 af1 = __builtin_bit_cast(bf16x8, w4f[((ot0 + 1) * 16 + ksr) * 64 + l]);
        bf16x8 bu = __builtin_bit_cast(bf16x8, Sp[(2 * ksr + khalf) * 32 + lane31]);
        acc[0] = MFMA32(af0, bu, acc[0]);
        acc[1] = MFMA32(af1, bu, acc[1]);
      }
    }
    __builtin_amdgcn_s_setprio(0);
    int pbase = (b * 2048 + j0 + lane31) * 256;
#pragma unroll
    for (int t2 = 0; t2 < 2; ++t2) {
#pragma unroll
      for (int q = 0; q < 4; ++q) {
        int ob = (ot0 + t2) * 32 + 8 * q + 4 * khalf;
        float4 v;
        v.x = fmaxf(acc[t2][4 * q + 0], 0.0f);
        v.y = fmaxf(acc[t2][4 * q + 1], 0.0f);
        v.z = fmaxf(acc[t2][4 * q + 2], 0.0f);
        v.w = fmaxf(acc[t2][4 * q + 3], 0.0f);
        *(float4*)(out + pbase + ob) = v;
      }
    }
  }
}

extern "C" void kernel_launch(void* const* d_in, const int* in_sizes, int n_in,
                              void* d_out, int out_size, void* d_ws, size_t ws_size,
                              hipStream_t stream) {
  const float* x  = (const float*)d_in[0];
  const float* W1 = (const float*)d_in[1];
  const float* b1 = (const float*)d_in[2];
  const float* W2 = (const float*)d_in[3];
  const float* b2 = (const float*)d_in[4];
  const float* W3 = (const float*)d_in[5];
  const float* b3 = (const float*)d_in[6];
  const float* W4 = (const float*)d_in[7];
  const float* b4 = (const float*)d_in[8];
  unsigned short* ws = (unsigned short*)d_ws;

  prep_kernel<<<68, 256, 0, stream>>>(W1, b1, W2, b2, W3, b3, W4, b4, ws);
  chain_kernel<<<1024, 256, 0, stream>>>(x, ws, (float*)d_out);
}